// Round 6
// baseline (650.358 us; speedup 1.0000x reference)
//
#include <hip/hip_runtime.h>

#define N_NODES 100000
#define N_EDGES 1600000
#define NFEAT 256
#define NHID 64
#define NOUT 16
#define NB_SCAN 391   // ceil(N_NODES/256)
#define NBUCK 782     // ceil(N_NODES/128), 128 dst-nodes per bucket

// ---------------------------------------------------------------------------
// CSR build step 1: histogram of dst
// ---------------------------------------------------------------------------
__global__ __launch_bounds__(256) void hist_kernel(const int* __restrict__ dst,
                                                   int* __restrict__ counts) {
  int t = blockIdx.x * blockDim.x + threadIdx.x;
  if (t < N_EDGES) atomicAdd(&counts[dst[t]], 1);
}

// ---------------------------------------------------------------------------
// CSR build step 2a: per-256-block inclusive scan of counts
// ---------------------------------------------------------------------------
__global__ __launch_bounds__(256) void scan1_kernel(
    const int* __restrict__ counts, int* __restrict__ scanTmp,
    int* __restrict__ blockSums) {
  __shared__ int s[256];
  int t = threadIdx.x;
  int i = blockIdx.x * 256 + t;
  int v = (i < N_NODES) ? counts[i] : 0;
  s[t] = v;
  __syncthreads();
  for (int off = 1; off < 256; off <<= 1) {
    int x = (t >= off) ? s[t - off] : 0;
    __syncthreads();
    s[t] += x;
    __syncthreads();
  }
  if (i < N_NODES) scanTmp[i] = s[t];
  if (t == 255) blockSums[blockIdx.x] = s[255];
}

// ---------------------------------------------------------------------------
// CSR build step 2b: single-block exclusive scan of block sums (NB_SCAN<=512)
// ---------------------------------------------------------------------------
__global__ __launch_bounds__(512) void scan2_kernel(
    const int* __restrict__ blockSums, int* __restrict__ blockOff) {
  __shared__ int s[512];
  int t = threadIdx.x;
  int v = (t < NB_SCAN) ? blockSums[t] : 0;
  s[t] = v;
  __syncthreads();
  for (int off = 1; off < 512; off <<= 1) {
    int x = (t >= off) ? s[t - off] : 0;
    __syncthreads();
    s[t] += x;
    __syncthreads();
  }
  if (t < NB_SCAN) blockOff[t] = s[t] - v;  // exclusive
}

// ---------------------------------------------------------------------------
// CSR build step 2c: row_start = exclusive scan; also init bucket cursors
// ---------------------------------------------------------------------------
__global__ __launch_bounds__(256) void scan3_kernel(
    const int* __restrict__ scanTmp, const int* __restrict__ counts,
    const int* __restrict__ blockOff, int* __restrict__ row_start,
    int* __restrict__ bcur) {
  int i = blockIdx.x * 256 + threadIdx.x;
  if (i < N_NODES) {
    int rs = scanTmp[i] - counts[i] + blockOff[blockIdx.x];
    row_start[i] = rs;
    if ((i & 127) == 0) bcur[i >> 7] = rs;  // bucket cursor = bucket base
  }
}

// ---------------------------------------------------------------------------
// Sort phase 1: scatter edges into 128-node dst-buckets.
// Bucket write streams are append-only -> ~782 active lines (L2-resident)
// -> HBM writes ~= payload (12.8 MB), not one line per store.
// dst&127 packed into bits 25..31 of x (src fits in 17 bits).
// ---------------------------------------------------------------------------
__global__ __launch_bounds__(256) void bucket_scatter_kernel(
    const int* __restrict__ src, const int* __restrict__ dst,
    const float* __restrict__ edge_val, int* __restrict__ bcur,
    int2* __restrict__ tmp_vs) {
  int t = blockIdx.x * blockDim.x + threadIdx.x;
  if (t >= N_EDGES) return;
  int d = dst[t];
  int p = atomicAdd(&bcur[d >> 7], 1);
  int2 vs;
  vs.x = src[t] | ((d & 127) << 25);
  vs.y = __float_as_int(edge_val[t]);
  tmp_vs[p] = vs;
}

// ---------------------------------------------------------------------------
// Sort phase 2: within-bucket counting sort to exact CSR position.
// One block per bucket; 128 LDS cursors; output window ~16 KB (L2-resident).
// ---------------------------------------------------------------------------
__global__ __launch_bounds__(256) void bucket_sort_kernel(
    const int2* __restrict__ tmp_vs, const int* __restrict__ row_start,
    int2* __restrict__ sorted_vs) {
  __shared__ int cur[128];
  int b = blockIdx.x;
  int t = threadIdx.x;
  int base = b << 7;
  if (t < 128) {
    int node = base + t;
    cur[t] = (node < N_NODES) ? row_start[node] : N_EDGES;
  }
  __syncthreads();
  int bstart = row_start[base];
  int bend = (b == NBUCK - 1) ? N_EDGES : row_start[base + 128];
  for (int e = bstart + t; e < bend; e += 256) {
    int2 vs = tmp_vs[e];
    int dlow = ((unsigned)vs.x) >> 25;
    int p = atomicAdd(&cur[dlow], 1);
    int2 o;
    o.x = vs.x & 0x1FFFFFF;
    o.y = vs.y;
    sorted_vs[p] = o;
  }
}

// ---------------------------------------------------------------------------
// K1: support1 = emb @ W1   [100000,256] @ [256,64]
// Block = 64 rows x 4 waves; wave wq owns col-quarter [wq*16, wq*16+16).
// ---------------------------------------------------------------------------
__global__ __launch_bounds__(256) void gemm1_kernel(
    const float* __restrict__ emb, const float* __restrict__ W1,
    float* __restrict__ out) {
  int lane = threadIdx.x & 63;
  int wq = __builtin_amdgcn_readfirstlane(threadIdx.x >> 6);
  int row = blockIdx.x * 64 + lane;
  int rclamp = row < N_NODES ? row : (N_NODES - 1);
  const float* er = emb + (size_t)rclamp * NFEAT;
  const float* w1q = W1 + wq * 16;  // scalar base

  float acc[16];
#pragma unroll
  for (int c = 0; c < 16; ++c) acc[c] = 0.f;

  for (int k0 = 0; k0 < NFEAT; k0 += 16) {
    float eb[16];
#pragma unroll
    for (int q = 0; q < 4; ++q)
      *(float4*)(eb + 4 * q) = *(const float4*)(er + k0 + 4 * q);
#pragma unroll
    for (int j = 0; j < 16; ++j) {
      const float* w = w1q + (size_t)(k0 + j) * NHID;  // lane-invariant
#pragma unroll
      for (int c = 0; c < 16; ++c) acc[c] = fmaf(eb[j], w[c], acc[c]);
    }
  }

  if (row < N_NODES) {
    float* o = out + (size_t)row * NHID + wq * 16;
#pragma unroll
    for (int c = 0; c < 16; c += 4) {
      float4 v = {acc[c], acc[c + 1], acc[c + 2], acc[c + 3]};
      *(float4*)(o + c) = v;
    }
  }
}

// ---------------------------------------------------------------------------
// K2 (fused): wave per dst row.
//   acc[lane] = sum_e val_e * support1[src_e][lane]        (CSR, no atomics)
//   h = relu(acc + b1) * mask
//   support2[row][c] = sum_k h[k] * W2[k][c]               (LDS + shfl reduce)
// ---------------------------------------------------------------------------
__global__ __launch_bounds__(256) void spmm1_fused_kernel(
    const float* __restrict__ support1, const int2* __restrict__ sorted_vs,
    const int* __restrict__ row_start, const int* __restrict__ counts,
    const float* __restrict__ b1, const float* __restrict__ mask,
    const float* __restrict__ W2, float* __restrict__ support2) {
  int wave = (blockIdx.x * blockDim.x + threadIdx.x) >> 6;
  int lane = threadIdx.x & 63;
  int wib = threadIdx.x >> 6;
  if (wave >= N_NODES) return;  // exact grid: never taken
  int r = wave;
  int beg = row_start[r];
  int end = beg + counts[r];
  float acc = 0.f;
#pragma unroll 4
  for (int e = beg; e < end; ++e) {
    int2 vs = sorted_vs[e];
    acc = fmaf(__int_as_float(vs.y), support1[(size_t)vs.x * NHID + lane],
               acc);
  }
  float h = fmaxf(acc + b1[lane], 0.f) * mask[(size_t)r * NHID + lane];

  __shared__ float hsh[4][NHID];
  hsh[wib][lane] = h;
  __syncthreads();
  int q = lane >> 4;   // 0..3 : k-quarter
  int c = lane & 15;   // output col
  float p = 0.f;
#pragma unroll
  for (int i = 0; i < 16; ++i) {
    int k = q * 16 + i;
    p = fmaf(hsh[wib][k], W2[k * NOUT + c], p);
  }
  p += __shfl_xor(p, 16);
  p += __shfl_xor(p, 32);
  if (lane < 16) support2[(size_t)r * NOUT + lane] = p;
}

// ---------------------------------------------------------------------------
// K3: out[row][c] = sum_e val_e * support2[src_e][c] + b2[c]
// 16 lanes per row, 4 rows per wave. CSR, no atomics, no init pass.
// ---------------------------------------------------------------------------
__global__ __launch_bounds__(256) void spmm2_csr_kernel(
    const float* __restrict__ support2, const int2* __restrict__ sorted_vs,
    const int* __restrict__ row_start, const int* __restrict__ counts,
    const float* __restrict__ b2, float* __restrict__ out) {
  int t = blockIdx.x * blockDim.x + threadIdx.x;
  int r = t >> 4;
  int c = t & 15;
  if (r >= N_NODES) return;
  int beg = row_start[r];
  int end = beg + counts[r];
  float acc = 0.f;
#pragma unroll 4
  for (int e = beg; e < end; ++e) {
    int2 vs = sorted_vs[e];
    acc = fmaf(__int_as_float(vs.y), support2[(size_t)vs.x * NOUT + c], acc);
  }
  out[(size_t)r * NOUT + c] = acc + b2[c];
}

extern "C" void kernel_launch(void* const* d_in, const int* in_sizes, int n_in,
                              void* d_out, int out_size, void* d_ws,
                              size_t ws_size, hipStream_t stream) {
  const float* emb = (const float*)d_in[0];
  const float* W1 = (const float*)d_in[1];
  const float* b1 = (const float*)d_in[2];
  const float* W2 = (const float*)d_in[3];
  const float* b2 = (const float*)d_in[4];
  const float* edge_val = (const float*)d_in[5];
  const float* mask = (const float*)d_in[6];
  const int* esrc = (const int*)d_in[7];
  const int* edst = (const int*)d_in[8];

  // workspace layout (element offsets in 4-byte units; int2 slots 8B-aligned)
  float* ws = (float*)d_ws;
  float* support1 = ws;                               // 6,400,000 f
  int2* tmp_vs = (int2*)ws;                           // aliases support1
  int2* sorted_vs = (int2*)(ws + 6400000);            // 1,600,000 int2
  float* support2 = ws + 6400000 + 3200000;           // 1,600,000 f
  int* counts = (int*)(ws + 11200000);                // 100,000 i
  int* scanTmp = counts + 100000;                     // 100,000 i
  int* row_start = scanTmp + 100000;                  // 100,000 i
  int* blockSums = row_start + 100000;                // 512 i
  int* blockOff = blockSums + 512;                    // 512 i
  int* bcur = blockOff + 512;                         // 782 i
  float* out = (float*)d_out;

  hipMemsetAsync(counts, 0, N_NODES * sizeof(int), stream);

  // CSR build: hist -> scan -> bucket scatter -> within-bucket sort
  hist_kernel<<<(N_EDGES + 255) / 256, 256, 0, stream>>>(edst, counts);
  scan1_kernel<<<NB_SCAN, 256, 0, stream>>>(counts, scanTmp, blockSums);
  scan2_kernel<<<1, 512, 0, stream>>>(blockSums, blockOff);
  scan3_kernel<<<NB_SCAN, 256, 0, stream>>>(scanTmp, counts, blockOff,
                                            row_start, bcur);
  bucket_scatter_kernel<<<(N_EDGES + 255) / 256, 256, 0, stream>>>(
      esrc, edst, edge_val, bcur, tmp_vs);
  bucket_sort_kernel<<<NBUCK, 256, 0, stream>>>(tmp_vs, row_start, sorted_vs);

  // dense + sparse pipeline (gemm1 after sort: support1 aliases tmp_vs)
  gemm1_kernel<<<(N_NODES + 63) / 64, 256, 0, stream>>>(emb, W1, support1);
  spmm1_fused_kernel<<<N_NODES / 4, 256, 0, stream>>>(
      support1, sorted_vs, row_start, counts, b1, mask, W2, support2);
  spmm2_csr_kernel<<<(N_NODES * NOUT + 255) / 256, 256, 0, stream>>>(
      support2, sorted_vs, row_start, counts, b2, out);
}

// Round 7
// 228.858 us; speedup vs baseline: 2.8417x; 2.8417x over previous
//
#include <hip/hip_runtime.h>

#define N_NODES 100000
#define N_EDGES 1600000
#define NFEAT 256
#define NHID 64
#define NOUT 16
#define BSIZE 256            // dst-nodes per bucket
#define NBUCK 391            // ceil(N_NODES/256)
#define CHUNK 4096           // edges per chunk
#define NCHUNK 391           // ceil(N_EDGES/4096)
#define MATN (NBUCK * NCHUNK)
#define MSCAN_NB 598         // ceil(MATN/256)

// ---------------------------------------------------------------------------
// S1: per-chunk bucket histogram -> histMat[bucket*NCHUNK + chunk]
// ---------------------------------------------------------------------------
__global__ __launch_bounds__(256) void histB_kernel(
    const int* __restrict__ dst, int* __restrict__ histMat) {
  __shared__ int hist[NBUCK];
  int t = threadIdx.x;
  int ch = blockIdx.x;
  if (t < NBUCK) hist[t] = 0;
  if (t + 256 < NBUCK) hist[t + 256] = 0;
  __syncthreads();
  int base = ch * CHUNK;
#pragma unroll
  for (int i = 0; i < CHUNK / 256; ++i) {
    int e = base + i * 256 + t;
    if (e < N_EDGES) atomicAdd(&hist[dst[e] >> 8], 1);
  }
  __syncthreads();
  if (t < NBUCK) histMat[t * NCHUNK + ch] = hist[t];
  if (t + 256 < NBUCK) histMat[(t + 256) * NCHUNK + ch] = hist[t + 256];
}

// ---------------------------------------------------------------------------
// S2a: per-256-block scan of histMat -> exclusive-within-block + blockSums
// ---------------------------------------------------------------------------
__global__ __launch_bounds__(256) void mscan1_kernel(
    const int* __restrict__ histMat, int* __restrict__ scanTmp,
    int* __restrict__ blockSums) {
  __shared__ int s[256];
  int t = threadIdx.x;
  int i = blockIdx.x * 256 + t;
  int v = (i < MATN) ? histMat[i] : 0;
  s[t] = v;
  __syncthreads();
  for (int off = 1; off < 256; off <<= 1) {
    int x = (t >= off) ? s[t - off] : 0;
    __syncthreads();
    s[t] += x;
    __syncthreads();
  }
  if (i < MATN) scanTmp[i] = s[t] - v;  // exclusive within block
  if (t == 255) blockSums[blockIdx.x] = s[255];
}

// ---------------------------------------------------------------------------
// S2b: single-block exclusive scan of MSCAN_NB block sums (<=1024)
// ---------------------------------------------------------------------------
__global__ __launch_bounds__(1024) void mscan2_kernel(
    const int* __restrict__ blockSums, int* __restrict__ blockOff) {
  __shared__ int s[1024];
  int t = threadIdx.x;
  int v = (t < MSCAN_NB) ? blockSums[t] : 0;
  s[t] = v;
  __syncthreads();
  for (int off = 1; off < 1024; off <<= 1) {
    int x = (t >= off) ? s[t - off] : 0;
    __syncthreads();
    s[t] += x;
    __syncthreads();
  }
  if (t < MSCAN_NB) blockOff[t] = s[t] - v;  // exclusive
}

// ---------------------------------------------------------------------------
// S2c: mEx[i] = scanTmp[i] + blockOff[block]   (in-place over histMat)
// ---------------------------------------------------------------------------
__global__ __launch_bounds__(256) void mscan3_kernel(
    const int* __restrict__ scanTmp, const int* __restrict__ blockOff,
    int* __restrict__ mEx) {
  int i = blockIdx.x * 256 + threadIdx.x;
  if (i < MATN) mEx[i] = scanTmp[i] + blockOff[blockIdx.x];
}

// ---------------------------------------------------------------------------
// S3: scatter edges into bucket-grouped tmp_vs. No global atomics: each
// (bucket,chunk) range is exclusively owned by this block (from mEx).
// XCD-bijective chunk swizzle keeps run-adjacent writers on one XCD.
// dlow = dst&255 packed into bits 17..24 of x (src < 2^17).
// ---------------------------------------------------------------------------
__global__ __launch_bounds__(256) void scatter2_kernel(
    const int* __restrict__ src, const int* __restrict__ dst,
    const float* __restrict__ edge_val, const int* __restrict__ mEx,
    int2* __restrict__ tmp_vs) {
  __shared__ int cur[NBUCK];
  int t = threadIdx.x;
  int bid = blockIdx.x;
  // bijective XCD swizzle: q=NCHUNK/8, r=NCHUNK%8
  int xcd = bid & 7;
  int q = NCHUNK >> 3, r = NCHUNK & 7;
  int ch = (xcd < r ? xcd * (q + 1) : r * (q + 1) + (xcd - r) * q) + (bid >> 3);
  if (t < NBUCK) cur[t] = mEx[t * NCHUNK + ch];
  if (t + 256 < NBUCK) cur[t + 256] = mEx[(t + 256) * NCHUNK + ch];
  __syncthreads();
  int base = ch * CHUNK;
#pragma unroll
  for (int i = 0; i < CHUNK / 256; ++i) {
    int e = base + i * 256 + t;
    if (e < N_EDGES) {
      int d = dst[e];
      int p = atomicAdd(&cur[d >> 8], 1);  // LDS atomic
      int2 vs;
      vs.x = src[e] | ((d & 255) << 17);
      vs.y = __float_as_int(edge_val[e]);
      tmp_vs[p] = vs;
    }
  }
}

// ---------------------------------------------------------------------------
// S4: within-bucket counting sort. One block per bucket (256 nodes):
// pass1 counts nodes in LDS, local scan -> row_start/counts written here,
// pass2 scatters into exact CSR slots (~32 KB L2-resident window).
// ---------------------------------------------------------------------------
__global__ __launch_bounds__(256) void bucket_sort_kernel(
    const int2* __restrict__ tmp_vs, const int* __restrict__ mEx,
    int2* __restrict__ sorted_vs, int* __restrict__ row_start,
    int* __restrict__ counts) {
  __shared__ int cnt[256], scn[256], cur[256];
  int b = blockIdx.x;
  int t = threadIdx.x;
  int bstart = mEx[b * NCHUNK];
  int bend = (b + 1 < NBUCK) ? mEx[(b + 1) * NCHUNK] : N_EDGES;
  cnt[t] = 0;
  __syncthreads();
  for (int e = bstart + t; e < bend; e += 256)
    atomicAdd(&cnt[((unsigned)tmp_vs[e].x) >> 17], 1);
  __syncthreads();
  scn[t] = cnt[t];
  __syncthreads();
  for (int off = 1; off < 256; off <<= 1) {
    int x = (t >= off) ? scn[t - off] : 0;
    __syncthreads();
    scn[t] += x;
    __syncthreads();
  }
  int excl = scn[t] - cnt[t];
  cur[t] = bstart + excl;
  int node = (b << 8) + t;
  if (node < N_NODES) {
    row_start[node] = bstart + excl;
    counts[node] = cnt[t];
  }
  __syncthreads();
  for (int e = bstart + t; e < bend; e += 256) {
    int2 vs = tmp_vs[e];
    int dlow = ((unsigned)vs.x) >> 17;
    int p = atomicAdd(&cur[dlow], 1);
    int2 o;
    o.x = vs.x & 0x1FFFF;
    o.y = vs.y;
    sorted_vs[p] = o;
  }
}

// ---------------------------------------------------------------------------
// K1: support1 = emb @ W1   [100000,256] @ [256,64]
// Block = 64 rows x 4 waves; wave wq owns col-quarter [wq*16, wq*16+16).
// ---------------------------------------------------------------------------
__global__ __launch_bounds__(256) void gemm1_kernel(
    const float* __restrict__ emb, const float* __restrict__ W1,
    float* __restrict__ out) {
  int lane = threadIdx.x & 63;
  int wq = __builtin_amdgcn_readfirstlane(threadIdx.x >> 6);
  int row = blockIdx.x * 64 + lane;
  int rclamp = row < N_NODES ? row : (N_NODES - 1);
  const float* er = emb + (size_t)rclamp * NFEAT;
  const float* w1q = W1 + wq * 16;  // scalar base

  float acc[16];
#pragma unroll
  for (int c = 0; c < 16; ++c) acc[c] = 0.f;

  for (int k0 = 0; k0 < NFEAT; k0 += 16) {
    float eb[16];
#pragma unroll
    for (int q = 0; q < 4; ++q)
      *(float4*)(eb + 4 * q) = *(const float4*)(er + k0 + 4 * q);
#pragma unroll
    for (int j = 0; j < 16; ++j) {
      const float* w = w1q + (size_t)(k0 + j) * NHID;  // lane-invariant
#pragma unroll
      for (int c = 0; c < 16; ++c) acc[c] = fmaf(eb[j], w[c], acc[c]);
    }
  }

  if (row < N_NODES) {
    float* o = out + (size_t)row * NHID + wq * 16;
#pragma unroll
    for (int c = 0; c < 16; c += 4) {
      float4 v = {acc[c], acc[c + 1], acc[c + 2], acc[c + 3]};
      *(float4*)(o + c) = v;
    }
  }
}

// ---------------------------------------------------------------------------
// K2 (fused): wave per dst row.
//   acc[lane] = sum_e val_e * support1[src_e][lane]        (CSR, no atomics)
//   h = relu(acc + b1) * mask
//   support2[row][c] = sum_k h[k] * W2[k][c]               (LDS + shfl reduce)
// ---------------------------------------------------------------------------
__global__ __launch_bounds__(256) void spmm1_fused_kernel(
    const float* __restrict__ support1, const int2* __restrict__ sorted_vs,
    const int* __restrict__ row_start, const int* __restrict__ counts,
    const float* __restrict__ b1, const float* __restrict__ mask,
    const float* __restrict__ W2, float* __restrict__ support2) {
  int wave = (blockIdx.x * blockDim.x + threadIdx.x) >> 6;
  int lane = threadIdx.x & 63;
  int wib = threadIdx.x >> 6;
  if (wave >= N_NODES) return;  // exact grid: never taken
  int r = wave;
  int beg = row_start[r];
  int end = beg + counts[r];
  float acc = 0.f;
#pragma unroll 4
  for (int e = beg; e < end; ++e) {
    int2 vs = sorted_vs[e];
    acc = fmaf(__int_as_float(vs.y), support1[(size_t)vs.x * NHID + lane],
               acc);
  }
  float h = fmaxf(acc + b1[lane], 0.f) * mask[(size_t)r * NHID + lane];

  __shared__ float hsh[4][NHID];
  hsh[wib][lane] = h;
  __syncthreads();
  int q = lane >> 4;   // 0..3 : k-quarter
  int c = lane & 15;   // output col
  float p = 0.f;
#pragma unroll
  for (int i = 0; i < 16; ++i) {
    int k = q * 16 + i;
    p = fmaf(hsh[wib][k], W2[k * NOUT + c], p);
  }
  p += __shfl_xor(p, 16);
  p += __shfl_xor(p, 32);
  if (lane < 16) support2[(size_t)r * NOUT + lane] = p;
}

// ---------------------------------------------------------------------------
// K3: out[row][c] = sum_e val_e * support2[src_e][c] + b2[c]
// 16 lanes per row, 4 rows per wave. CSR, no atomics, no init pass.
// ---------------------------------------------------------------------------
__global__ __launch_bounds__(256) void spmm2_csr_kernel(
    const float* __restrict__ support2, const int2* __restrict__ sorted_vs,
    const int* __restrict__ row_start, const int* __restrict__ counts,
    const float* __restrict__ b2, float* __restrict__ out) {
  int t = blockIdx.x * blockDim.x + threadIdx.x;
  int r = t >> 4;
  int c = t & 15;
  if (r >= N_NODES) return;
  int beg = row_start[r];
  int end = beg + counts[r];
  float acc = 0.f;
#pragma unroll 4
  for (int e = beg; e < end; ++e) {
    int2 vs = sorted_vs[e];
    acc = fmaf(__int_as_float(vs.y), support2[(size_t)vs.x * NOUT + c], acc);
  }
  out[(size_t)r * NOUT + c] = acc + b2[c];
}

extern "C" void kernel_launch(void* const* d_in, const int* in_sizes, int n_in,
                              void* d_out, int out_size, void* d_ws,
                              size_t ws_size, hipStream_t stream) {
  const float* emb = (const float*)d_in[0];
  const float* W1 = (const float*)d_in[1];
  const float* b1 = (const float*)d_in[2];
  const float* W2 = (const float*)d_in[3];
  const float* b2 = (const float*)d_in[4];
  const float* edge_val = (const float*)d_in[5];
  const float* mask = (const float*)d_in[6];
  const int* esrc = (const int*)d_in[7];
  const int* edst = (const int*)d_in[8];

  // workspace layout (4-byte units)
  float* ws = (float*)d_ws;
  float* support1 = ws;                               // 6,400,000 f
  int2* tmp_vs = (int2*)ws;                           // aliases support1
  int2* sorted_vs = (int2*)(ws + 6400000);            // 1,600,000 int2
  float* support2 = ws + 9600000;                     // 1,600,000 f
  int* scanTmpM = (int*)support2;                     // aliases support2 (used before spmm1)
  int* row_start = (int*)(ws + 11200000);             // 100,000 i
  int* counts = row_start + 100000;                   // 100,000 i
  int* histMat = counts + 100000;                     // 152,881 i (becomes mEx)
  int* mBlockSums = histMat + MATN;                   // 1024 i
  int* mBlockOff = mBlockSums + 1024;                 // 1024 i
  float* out = (float*)d_out;

  // CSR build: chunk-histogram -> matrix scan -> ownership scatter -> sort
  histB_kernel<<<NCHUNK, 256, 0, stream>>>(edst, histMat);
  mscan1_kernel<<<MSCAN_NB, 256, 0, stream>>>(histMat, scanTmpM, mBlockSums);
  mscan2_kernel<<<1, 1024, 0, stream>>>(mBlockSums, mBlockOff);
  mscan3_kernel<<<MSCAN_NB, 256, 0, stream>>>(scanTmpM, mBlockOff, histMat);
  scatter2_kernel<<<NCHUNK, 256, 0, stream>>>(esrc, edst, edge_val, histMat,
                                              tmp_vs);
  bucket_sort_kernel<<<NBUCK, 256, 0, stream>>>(tmp_vs, histMat, sorted_vs,
                                                row_start, counts);

  // dense + sparse pipeline (gemm1 after sort: support1 aliases tmp_vs)
  gemm1_kernel<<<(N_NODES + 63) / 64, 256, 0, stream>>>(emb, W1, support1);
  spmm1_fused_kernel<<<N_NODES / 4, 256, 0, stream>>>(
      support1, sorted_vs, row_start, counts, b1, mask, W2, support2);
  spmm2_csr_kernel<<<(N_NODES * NOUT + 255) / 256, 256, 0, stream>>>(
      support2, sorted_vs, row_start, counts, b2, out);
}

// Round 8
// 220.414 us; speedup vs baseline: 2.9506x; 1.0383x over previous
//
#include <hip/hip_runtime.h>

#define N_NODES 100000
#define N_EDGES 1600000
#define NFEAT 256
#define NHID 64
#define NOUT 16
#define BSIZE 256            // dst-nodes per bucket
#define NBUCK 391            // ceil(N_NODES/256)
#define CHUNK 4096           // edges per chunk
#define NCHUNK 391           // ceil(N_EDGES/4096)
#define MATN (NBUCK * NCHUNK)
#define MSCAN_NB 598         // ceil(MATN/256)

__device__ __forceinline__ unsigned short f2bf(float f) {
  unsigned u = __float_as_uint(f);
  unsigned r = (u + 0x7FFF + ((u >> 16) & 1)) >> 16;  // RNE
  return (unsigned short)r;
}
__device__ __forceinline__ float bf2f(unsigned short b) {
  return __uint_as_float(((unsigned)b) << 16);
}

// ---------------------------------------------------------------------------
// S1: per-chunk bucket histogram -> histMat[bucket*NCHUNK + chunk]
// ---------------------------------------------------------------------------
__global__ __launch_bounds__(256) void histB_kernel(
    const int* __restrict__ dst, int* __restrict__ histMat) {
  __shared__ int hist[NBUCK];
  int t = threadIdx.x;
  int ch = blockIdx.x;
  if (t < NBUCK) hist[t] = 0;
  if (t + 256 < NBUCK) hist[t + 256] = 0;
  __syncthreads();
  int base = ch * CHUNK;
#pragma unroll
  for (int i = 0; i < CHUNK / 256; ++i) {
    int e = base + i * 256 + t;
    if (e < N_EDGES) atomicAdd(&hist[dst[e] >> 8], 1);
  }
  __syncthreads();
  if (t < NBUCK) histMat[t * NCHUNK + ch] = hist[t];
  if (t + 256 < NBUCK) histMat[(t + 256) * NCHUNK + ch] = hist[t + 256];
}

// ---------------------------------------------------------------------------
// S2a: per-256-block scan of histMat -> exclusive-within-block + blockSums
// ---------------------------------------------------------------------------
__global__ __launch_bounds__(256) void mscan1_kernel(
    const int* __restrict__ histMat, int* __restrict__ scanTmp,
    int* __restrict__ blockSums) {
  __shared__ int s[256];
  int t = threadIdx.x;
  int i = blockIdx.x * 256 + t;
  int v = (i < MATN) ? histMat[i] : 0;
  s[t] = v;
  __syncthreads();
  for (int off = 1; off < 256; off <<= 1) {
    int x = (t >= off) ? s[t - off] : 0;
    __syncthreads();
    s[t] += x;
    __syncthreads();
  }
  if (i < MATN) scanTmp[i] = s[t] - v;  // exclusive within block
  if (t == 255) blockSums[blockIdx.x] = s[255];
}

// ---------------------------------------------------------------------------
// S2b: single-block exclusive scan of MSCAN_NB block sums (<=1024)
// ---------------------------------------------------------------------------
__global__ __launch_bounds__(1024) void mscan2_kernel(
    const int* __restrict__ blockSums, int* __restrict__ blockOff) {
  __shared__ int s[1024];
  int t = threadIdx.x;
  int v = (t < MSCAN_NB) ? blockSums[t] : 0;
  s[t] = v;
  __syncthreads();
  for (int off = 1; off < 1024; off <<= 1) {
    int x = (t >= off) ? s[t - off] : 0;
    __syncthreads();
    s[t] += x;
    __syncthreads();
  }
  if (t < MSCAN_NB) blockOff[t] = s[t] - v;  // exclusive
}

// ---------------------------------------------------------------------------
// S2c: mEx[i] = scanTmp[i] + blockOff[block]   (in-place over histMat)
// ---------------------------------------------------------------------------
__global__ __launch_bounds__(256) void mscan3_kernel(
    const int* __restrict__ scanTmp, const int* __restrict__ blockOff,
    int* __restrict__ mEx) {
  int i = blockIdx.x * 256 + threadIdx.x;
  if (i < MATN) mEx[i] = scanTmp[i] + blockOff[blockIdx.x];
}

// ---------------------------------------------------------------------------
// S3: scatter edges into bucket-grouped tmp_vs. No global atomics: each
// (bucket,chunk) range is exclusively owned by this block (from mEx).
// dlow = dst&255 packed into bits 17..24 of x (src < 2^17).
// ---------------------------------------------------------------------------
__global__ __launch_bounds__(256) void scatter2_kernel(
    const int* __restrict__ src, const int* __restrict__ dst,
    const float* __restrict__ edge_val, const int* __restrict__ mEx,
    int2* __restrict__ tmp_vs) {
  __shared__ int cur[NBUCK];
  int t = threadIdx.x;
  int bid = blockIdx.x;
  // bijective XCD swizzle: q=NCHUNK/8, r=NCHUNK%8
  int xcd = bid & 7;
  int q = NCHUNK >> 3, r = NCHUNK & 7;
  int ch = (xcd < r ? xcd * (q + 1) : r * (q + 1) + (xcd - r) * q) + (bid >> 3);
  if (t < NBUCK) cur[t] = mEx[t * NCHUNK + ch];
  if (t + 256 < NBUCK) cur[t + 256] = mEx[(t + 256) * NCHUNK + ch];
  __syncthreads();
  int base = ch * CHUNK;
#pragma unroll
  for (int i = 0; i < CHUNK / 256; ++i) {
    int e = base + i * 256 + t;
    if (e < N_EDGES) {
      int d = dst[e];
      int p = atomicAdd(&cur[d >> 8], 1);  // LDS atomic
      int2 vs;
      vs.x = src[e] | ((d & 255) << 17);
      vs.y = __float_as_int(edge_val[e]);
      tmp_vs[p] = vs;
    }
  }
}

// ---------------------------------------------------------------------------
// S4: within-bucket counting sort. One block per bucket (256 nodes):
// pass1 counts nodes in LDS, local scan -> row_start/counts written here,
// pass2 scatters into exact CSR slots (~32 KB L2-resident window).
// ---------------------------------------------------------------------------
__global__ __launch_bounds__(256) void bucket_sort_kernel(
    const int2* __restrict__ tmp_vs, const int* __restrict__ mEx,
    int2* __restrict__ sorted_vs, int* __restrict__ row_start,
    int* __restrict__ counts) {
  __shared__ int cnt[256], scn[256], cur[256];
  int b = blockIdx.x;
  int t = threadIdx.x;
  int bstart = mEx[b * NCHUNK];
  int bend = (b + 1 < NBUCK) ? mEx[(b + 1) * NCHUNK] : N_EDGES;
  cnt[t] = 0;
  __syncthreads();
  for (int e = bstart + t; e < bend; e += 256)
    atomicAdd(&cnt[((unsigned)tmp_vs[e].x) >> 17], 1);
  __syncthreads();
  scn[t] = cnt[t];
  __syncthreads();
  for (int off = 1; off < 256; off <<= 1) {
    int x = (t >= off) ? scn[t - off] : 0;
    __syncthreads();
    scn[t] += x;
    __syncthreads();
  }
  int excl = scn[t] - cnt[t];
  cur[t] = bstart + excl;
  int node = (b << 8) + t;
  if (node < N_NODES) {
    row_start[node] = bstart + excl;
    counts[node] = cnt[t];
  }
  __syncthreads();
  for (int e = bstart + t; e < bend; e += 256) {
    int2 vs = tmp_vs[e];
    int dlow = ((unsigned)vs.x) >> 17;
    int p = atomicAdd(&cur[dlow], 1);
    int2 o;
    o.x = vs.x & 0x1FFFF;
    o.y = vs.y;
    sorted_vs[p] = o;
  }
}

// ---------------------------------------------------------------------------
// K1: support1 = bf16(emb @ W1)   [100000,256] @ [256,64]
// Block = 64 rows x 4 waves; wave wq owns col-quarter [wq*16, wq*16+16).
// bf16 output halves the spmm1 gather traffic (256B -> 128B per edge).
// ---------------------------------------------------------------------------
__global__ __launch_bounds__(256) void gemm1_kernel(
    const float* __restrict__ emb, const float* __restrict__ W1,
    unsigned short* __restrict__ out) {
  int lane = threadIdx.x & 63;
  int wq = __builtin_amdgcn_readfirstlane(threadIdx.x >> 6);
  int row = blockIdx.x * 64 + lane;
  int rclamp = row < N_NODES ? row : (N_NODES - 1);
  const float* er = emb + (size_t)rclamp * NFEAT;
  const float* w1q = W1 + wq * 16;  // scalar base

  float acc[16];
#pragma unroll
  for (int c = 0; c < 16; ++c) acc[c] = 0.f;

  for (int k0 = 0; k0 < NFEAT; k0 += 16) {
    float eb[16];
#pragma unroll
    for (int q = 0; q < 4; ++q)
      *(float4*)(eb + 4 * q) = *(const float4*)(er + k0 + 4 * q);
#pragma unroll
    for (int j = 0; j < 16; ++j) {
      const float* w = w1q + (size_t)(k0 + j) * NHID;  // lane-invariant
#pragma unroll
      for (int c = 0; c < 16; ++c) acc[c] = fmaf(eb[j], w[c], acc[c]);
    }
  }

  if (row < N_NODES) {
    unsigned short* o = out + (size_t)row * NHID + wq * 16;
    ushort4 pk[4];
#pragma unroll
    for (int g = 0; g < 4; ++g) {
      pk[g].x = f2bf(acc[4 * g + 0]);
      pk[g].y = f2bf(acc[4 * g + 1]);
      pk[g].z = f2bf(acc[4 * g + 2]);
      pk[g].w = f2bf(acc[4 * g + 3]);
    }
    *(ushort4*)(o + 0) = pk[0];
    *(ushort4*)(o + 4) = pk[1];
    *(ushort4*)(o + 8) = pk[2];
    *(ushort4*)(o + 12) = pk[3];
  }
}

// ---------------------------------------------------------------------------
// K2 (fused): wave per dst row, bf16 gather (128B/edge).
//   acc[lane] = sum_e val_e * support1[src_e][lane]        (CSR, no atomics)
//   h = relu(acc + b1) * mask
//   support2[row][c] = sum_k h[k] * W2[k][c]               (LDS + shfl reduce)
// ---------------------------------------------------------------------------
__global__ __launch_bounds__(256) void spmm1_fused_kernel(
    const unsigned short* __restrict__ support1,
    const int2* __restrict__ sorted_vs, const int* __restrict__ row_start,
    const int* __restrict__ counts, const float* __restrict__ b1,
    const float* __restrict__ mask, const float* __restrict__ W2,
    float* __restrict__ support2) {
  int wave = (blockIdx.x * blockDim.x + threadIdx.x) >> 6;
  int lane = threadIdx.x & 63;
  int wib = threadIdx.x >> 6;
  if (wave >= N_NODES) return;  // exact grid: never taken
  int r = wave;
  int beg = row_start[r];
  int end = beg + counts[r];
  float acc = 0.f;
#pragma unroll 4
  for (int e = beg; e < end; ++e) {
    int2 vs = sorted_vs[e];
    acc = fmaf(__int_as_float(vs.y),
               bf2f(support1[(size_t)vs.x * NHID + lane]), acc);
  }
  float h = fmaxf(acc + b1[lane], 0.f) * mask[(size_t)r * NHID + lane];

  __shared__ float hsh[4][NHID];
  hsh[wib][lane] = h;
  __syncthreads();
  int q = lane >> 4;   // 0..3 : k-quarter
  int c = lane & 15;   // output col
  float p = 0.f;
#pragma unroll
  for (int i = 0; i < 16; ++i) {
    int k = q * 16 + i;
    p = fmaf(hsh[wib][k], W2[k * NOUT + c], p);
  }
  p += __shfl_xor(p, 16);
  p += __shfl_xor(p, 32);
  if (lane < 16) support2[(size_t)r * NOUT + lane] = p;
}

// ---------------------------------------------------------------------------
// K3: out[row][c] = sum_e val_e * support2[src_e][c] + b2[c]
// 16 lanes per row, 4 rows per wave. CSR, no atomics, no init pass.
// ---------------------------------------------------------------------------
__global__ __launch_bounds__(256) void spmm2_csr_kernel(
    const float* __restrict__ support2, const int2* __restrict__ sorted_vs,
    const int* __restrict__ row_start, const int* __restrict__ counts,
    const float* __restrict__ b2, float* __restrict__ out) {
  int t = blockIdx.x * blockDim.x + threadIdx.x;
  int r = t >> 4;
  int c = t & 15;
  if (r >= N_NODES) return;
  int beg = row_start[r];
  int end = beg + counts[r];
  float acc = 0.f;
#pragma unroll 4
  for (int e = beg; e < end; ++e) {
    int2 vs = sorted_vs[e];
    acc = fmaf(__int_as_float(vs.y), support2[(size_t)vs.x * NOUT + c], acc);
  }
  out[(size_t)r * NOUT + c] = acc + b2[c];
}

extern "C" void kernel_launch(void* const* d_in, const int* in_sizes, int n_in,
                              void* d_out, int out_size, void* d_ws,
                              size_t ws_size, hipStream_t stream) {
  const float* emb = (const float*)d_in[0];
  const float* W1 = (const float*)d_in[1];
  const float* b1 = (const float*)d_in[2];
  const float* W2 = (const float*)d_in[3];
  const float* b2 = (const float*)d_in[4];
  const float* edge_val = (const float*)d_in[5];
  const float* mask = (const float*)d_in[6];
  const int* esrc = (const int*)d_in[7];
  const int* edst = (const int*)d_in[8];

  // workspace layout (4-byte units)
  float* ws = (float*)d_ws;
  int2* tmp_vs = (int2*)ws;                           // 1,600,000 int2 (12.8MB)
  unsigned short* support1 = (unsigned short*)ws;     // aliases tmp_vs (12.8MB,
                                                      //  written after sort)
  int2* sorted_vs = (int2*)(ws + 6400000);            // 1,600,000 int2
  float* support2 = ws + 9600000;                     // 1,600,000 f
  int* scanTmpM = (int*)support2;                     // aliases support2 (dead
                                                      //  before spmm1 writes)
  int* row_start = (int*)(ws + 11200000);             // 100,000 i
  int* counts = row_start + 100000;                   // 100,000 i
  int* histMat = counts + 100000;                     // 152,881 i (becomes mEx)
  int* mBlockSums = histMat + MATN;                   // 1024 i
  int* mBlockOff = mBlockSums + 1024;                 // 1024 i
  float* out = (float*)d_out;

  // CSR build: chunk-histogram -> matrix scan -> ownership scatter -> sort
  histB_kernel<<<NCHUNK, 256, 0, stream>>>(edst, histMat);
  mscan1_kernel<<<MSCAN_NB, 256, 0, stream>>>(histMat, scanTmpM, mBlockSums);
  mscan2_kernel<<<1, 1024, 0, stream>>>(mBlockSums, mBlockOff);
  mscan3_kernel<<<MSCAN_NB, 256, 0, stream>>>(scanTmpM, mBlockOff, histMat);
  scatter2_kernel<<<NCHUNK, 256, 0, stream>>>(esrc, edst, edge_val, histMat,
                                              tmp_vs);
  bucket_sort_kernel<<<NBUCK, 256, 0, stream>>>(tmp_vs, histMat, sorted_vs,
                                                row_start, counts);

  // dense + sparse pipeline (gemm1 after sort: support1 aliases tmp_vs)
  gemm1_kernel<<<(N_NODES + 63) / 64, 256, 0, stream>>>(emb, W1, support1);
  spmm1_fused_kernel<<<N_NODES / 4, 256, 0, stream>>>(
      support1, sorted_vs, row_start, counts, b1, mask, W2, support2);
  spmm2_csr_kernel<<<(N_NODES * NOUT + 255) / 256, 256, 0, stream>>>(
      support2, sorted_vs, row_start, counts, b2, out);
}